// Round 1
// baseline (1535.538 us; speedup 1.0000x reference)
//
#include <hip/hip_runtime.h>
#include <math.h>

#define NN 20000   // nodes
#define NE 320000  // edges (without self-loops)
#define TT 8       // timesteps
#define FIN 32     // input features
#define HH 8       // heads (layer 1)
#define D1 256     // H*F layer-1 width
#define CD 32      // layer-2 width == LSTM hidden
#define LSTM_GRP 10

// ---------------- CSR build (once per launch; edges identical across t) ----------------

__global__ __launch_bounds__(256) void k_deg(const int* __restrict__ dst, int* __restrict__ deg) {
  int e = blockIdx.x * 256 + threadIdx.x;
  if (e < NE) atomicAdd(&deg[dst[e]], 1);
}

__global__ __launch_bounds__(1024) void k_scan(const int* __restrict__ deg,
                                               int* __restrict__ rowptr, int* __restrict__ fill) {
  __shared__ int sd[1024];
  __shared__ int carry_s;
  int tid = threadIdx.x;
  if (tid == 0) { carry_s = 0; rowptr[0] = 0; }
  __syncthreads();
  for (int base = 0; base < NN; base += 1024) {
    int i = base + tid;
    int v = (i < NN) ? deg[i] : 0;
    sd[tid] = v;
    __syncthreads();
    for (int off = 1; off < 1024; off <<= 1) {
      int t = (tid >= off) ? sd[tid - off] : 0;
      __syncthreads();
      sd[tid] += t;
      __syncthreads();
    }
    int incl = sd[tid];
    int carry = carry_s;
    if (i < NN) { rowptr[i + 1] = carry + incl; fill[i] = carry + incl - v; }
    __syncthreads();
    if (tid == 1023) carry_s = carry + sd[1023];
    __syncthreads();
  }
}

__global__ __launch_bounds__(256) void k_fill(const int* __restrict__ src, const int* __restrict__ dst,
                                              int* __restrict__ fill, int* __restrict__ csr) {
  int e = blockIdx.x * 256 + threadIdx.x;
  if (e < NE) {
    int pos = atomicAdd(&fill[dst[e]], 1);
    csr[pos] = src[e];
  }
}

// ---------------- GAT layer 1: h1 = x@W1 plus attention logits ----------------
// block = one node, thread j computes h1[n,j]; then per-head shuffle reduce for al_src/al_dst.

__global__ __launch_bounds__(256) void k_gemm1(const float* __restrict__ x, const float* __restrict__ W1,
    const float* __restrict__ as1, const float* __restrict__ ad1,
    float* __restrict__ h1, float* __restrict__ als, float* __restrict__ ald) {
  int n = blockIdx.x;
  int j = threadIdx.x;
  __shared__ float xr[FIN];
  if (j < FIN) xr[j] = x[n * FIN + j];
  __syncthreads();
  float acc = 0.f;
  #pragma unroll
  for (int k = 0; k < FIN; ++k) acc = fmaf(xr[k], W1[k * D1 + j], acc);
  h1[n * D1 + j] = acc;
  float vs = acc * as1[j];
  float vd = acc * ad1[j];
  #pragma unroll
  for (int m = 1; m < 32; m <<= 1) {
    vs += __shfl_xor(vs, m, 64);
    vd += __shfl_xor(vd, m, 64);
  }
  if ((j & 31) == 0) {
    als[n * HH + (j >> 5)] = vs;
    ald[n * HH + (j >> 5)] = vd;
  }
}

// ---------------- GAT layer 1 aggregation: wave per node, lane -> 4 features ----------------
// out = relu( (sum_e e*h1[src]) / (sum_e e) + b1 ), self-loop as the last iteration.

__global__ __launch_bounds__(256) void k_agg1(const float* __restrict__ h1,
    const float* __restrict__ als, const float* __restrict__ ald,
    const int* __restrict__ rowptr, const int* __restrict__ csr,
    const float* __restrict__ b1, float* __restrict__ out) {
  int lane = threadIdx.x & 63;
  int n = blockIdx.x * 4 + (threadIdx.x >> 6);
  int h = lane >> 3;                       // head of features [lane*4 .. lane*4+3]
  float ad = ald[n * HH + h];
  float4 acc = make_float4(0.f, 0.f, 0.f, 0.f);
  float den = 0.f;
  int beg = rowptr[n], end = rowptr[n + 1];
  int s_next = (beg < end) ? csr[beg] : n;
  for (int idx = beg; idx <= end; ++idx) {   // deg edges + 1 self-loop
    int s = s_next;
    s_next = (idx + 1 < end) ? csr[idx + 1] : n;
    float a = als[s * HH + h] + ad;
    a = a > 0.f ? a : 0.2f * a;              // leaky_relu(0.2)
    float e = __expf(a);
    float4 hv = *(const float4*)(h1 + s * D1 + lane * 4);
    acc.x = fmaf(e, hv.x, acc.x);
    acc.y = fmaf(e, hv.y, acc.y);
    acc.z = fmaf(e, hv.z, acc.z);
    acc.w = fmaf(e, hv.w, acc.w);
    den += e;
  }
  float inv = 1.f / den;
  int j = lane * 4;
  float4 bb = *(const float4*)(b1 + j);
  float4 o;
  o.x = fmaxf(fmaf(acc.x, inv, bb.x), 0.f);
  o.y = fmaxf(fmaf(acc.y, inv, bb.y), 0.f);
  o.z = fmaxf(fmaf(acc.z, inv, bb.z), 0.f);
  o.w = fmaxf(fmaf(acc.w, inv, bb.w), 0.f);
  *(float4*)(out + n * D1 + j) = o;
}

// ---------------- GAT layer 2 GEMM: h2 = rel1@W2 plus logits (1 head) ----------------
// block = 8 nodes x 32 threads; rel1 rows + W2 staged in LDS.

__global__ __launch_bounds__(256) void k_gemm2(const float* __restrict__ rel1, const float* __restrict__ W2,
    const float* __restrict__ as2, const float* __restrict__ ad2,
    float* __restrict__ h2, float* __restrict__ als, float* __restrict__ ald) {
  __shared__ float rows[8 * D1];
  __shared__ float w2s[D1 * CD];
  int tid = threadIdx.x;
  int n0 = blockIdx.x * 8;
  for (int i = tid; i < 8 * D1; i += 256) rows[i] = rel1[n0 * D1 + i];
  for (int i = tid; i < D1 * CD; i += 256) w2s[i] = W2[i];
  __syncthreads();
  int r = tid >> 5, f = tid & 31;
  const float* row = rows + r * D1;
  float acc = 0.f;
  #pragma unroll 8
  for (int k = 0; k < D1; ++k) acc = fmaf(row[k], w2s[k * CD + f], acc);
  int n = n0 + r;
  h2[n * CD + f] = acc;
  float vs = acc * as2[f];
  float vd = acc * ad2[f];
  #pragma unroll
  for (int m = 1; m < 32; m <<= 1) {
    vs += __shfl_xor(vs, m, 64);
    vd += __shfl_xor(vd, m, 64);
  }
  if (f == 0) { als[n] = vs; ald[n] = vd; }
}

// ---------------- GAT layer 2 aggregation: 32 threads per node ----------------

__global__ __launch_bounds__(256) void k_agg2(const float* __restrict__ h2,
    const float* __restrict__ als, const float* __restrict__ ald,
    const int* __restrict__ rowptr, const int* __restrict__ csr,
    const float* __restrict__ b2, float* __restrict__ out) {
  int tid = threadIdx.x;
  int r = tid >> 5, f = tid & 31;
  int n = blockIdx.x * 8 + r;
  float ad = ald[n];
  float acc = 0.f, den = 0.f;
  int beg = rowptr[n], end = rowptr[n + 1];
  int s_next = (beg < end) ? csr[beg] : n;
  for (int idx = beg; idx <= end; ++idx) {
    int s = s_next;
    s_next = (idx + 1 < end) ? csr[idx + 1] : n;
    float a = als[s] + ad;
    a = a > 0.f ? a : 0.2f * a;
    float e = __expf(a);
    acc = fmaf(e, h2[s * CD + f], acc);
    den += e;
  }
  out[n * CD + f] = acc / den + b2[f];   // no relu after layer 2
}

// ---------------- LSTM step: thread per (node, hidden k); weights transposed in LDS ----------------

__global__ __launch_bounds__(256) void k_lstm(const float* __restrict__ xt,
    const float* __restrict__ w_ih, const float* __restrict__ w_hh,
    const float* __restrict__ b_ih, const float* __restrict__ b_hh,
    float* __restrict__ h, float* __restrict__ c, float* __restrict__ out_t) {
  __shared__ float wiT[32 * 128];  // [j][row], row = gate*32 + k
  __shared__ float whT[32 * 128];
  __shared__ float xs[256];
  __shared__ float hs[256];
  int tid = threadIdx.x;
  for (int i = tid; i < 128 * 32; i += 256) {
    int row = i >> 5, j = i & 31;
    wiT[j * 128 + row] = w_ih[i];
    whT[j * 128 + row] = w_hh[i];
  }
  int r = tid >> 5, k = tid & 31;
  float bi = b_ih[k]      + b_hh[k];
  float bf = b_ih[32 + k] + b_hh[32 + k];
  float bg = b_ih[64 + k] + b_hh[64 + k];
  float bo = b_ih[96 + k] + b_hh[96 + k];
  for (int g = 0; g < LSTM_GRP; ++g) {
    int base = (blockIdx.x * LSTM_GRP + g) * 256;
    __syncthreads();                 // protect xs/hs reuse across groups
    xs[tid] = xt[base + tid];
    hs[tid] = h[base + tid];
    __syncthreads();
    float ai = bi, af = bf, ag = bg, ao = bo;
    const float* xr = xs + r * 32;
    const float* hr = hs + r * 32;
    #pragma unroll
    for (int j = 0; j < 32; ++j) {
      float xv = xr[j], hv = hr[j];
      const float* wi = wiT + j * 128 + k;
      const float* wh = whT + j * 128 + k;
      ai = fmaf(xv, wi[0],  fmaf(hv, wh[0],  ai));
      af = fmaf(xv, wi[32], fmaf(hv, wh[32], af));
      ag = fmaf(xv, wi[64], fmaf(hv, wh[64], ag));
      ao = fmaf(xv, wi[96], fmaf(hv, wh[96], ao));
    }
    float ii = 1.f / (1.f + __expf(-ai));
    float ff = 1.f / (1.f + __expf(-af));
    float gg = tanhf(ag);
    float oo = 1.f / (1.f + __expf(-ao));
    int gi = base + tid;
    float cn = fmaf(ff, c[gi], ii * gg);
    float hn = oo * tanhf(cn);
    c[gi] = cn;
    h[gi] = hn;
    out_t[gi] = hn;
  }
}

// ---------------- softmax over the node dimension, per (t, c), in place ----------------

__global__ __launch_bounds__(256) void k_softmax(float* __restrict__ out) {
  int t = blockIdx.x >> 5;
  int cc = blockIdx.x & 31;
  float* base = out + (size_t)t * NN * CD + cc;
  int tid = threadIdx.x;
  float s = 0.f;
  for (int n = tid; n < NN; n += 256) s += __expf(base[n * CD]);   // |h|<1: no max needed
  __shared__ float red[256];
  red[tid] = s;
  __syncthreads();
  for (int off = 128; off > 0; off >>= 1) {
    if (tid < off) red[tid] += red[tid + off];
    __syncthreads();
  }
  float inv = 1.f / red[0];
  for (int n = tid; n < NN; n += 256) base[n * CD] = __expf(base[n * CD]) * inv;
}

// ---------------- launch ----------------

extern "C" void kernel_launch(void* const* d_in, const int* in_sizes, int n_in,
                              void* d_out, int out_size, void* d_ws, size_t ws_size,
                              hipStream_t stream) {
  const float* x   = (const float*)d_in[0];
  const float* W1  = (const float*)d_in[1];
  const float* as1 = (const float*)d_in[2];
  const float* ad1 = (const float*)d_in[3];
  const float* b1  = (const float*)d_in[4];
  const float* W2  = (const float*)d_in[5];
  const float* as2 = (const float*)d_in[6];
  const float* ad2 = (const float*)d_in[7];
  const float* b2  = (const float*)d_in[8];
  const float* wih = (const float*)d_in[9];
  const float* whh = (const float*)d_in[10];
  const float* bih = (const float*)d_in[11];
  const float* bhh = (const float*)d_in[12];
  const int*   ei  = (const int*)d_in[13];
  const int* srcp = ei;
  const int* dstp = ei + NE;
  float* out = (float*)d_out;

  float* ws = (float*)d_ws;
  float* h1   = ws;  ws += (size_t)NN * D1;
  float* rel1 = ws;  ws += (size_t)NN * D1;
  float* al1s = ws;  ws += NN * HH;
  float* al1d = ws;  ws += NN * HH;
  float* h2   = ws;  ws += NN * CD;
  float* al2s = ws;  ws += NN;
  float* al2d = ws;  ws += NN;
  float* agg2 = ws;  ws += NN * CD;
  float* hb   = ws;  ws += NN * CD;
  float* cb   = ws;  ws += NN * CD;
  int* rowptr = (int*)ws;
  int* fill   = rowptr + NN + 1;
  int* csr    = fill + NN;
  int* deg    = csr + NE;

  hipMemsetAsync(deg, 0, NN * sizeof(int), stream);
  hipMemsetAsync(hb, 0, NN * CD * sizeof(float), stream);
  hipMemsetAsync(cb, 0, NN * CD * sizeof(float), stream);

  k_deg<<<(NE + 255) / 256, 256, 0, stream>>>(dstp, deg);
  k_scan<<<1, 1024, 0, stream>>>(deg, rowptr, fill);
  k_fill<<<(NE + 255) / 256, 256, 0, stream>>>(srcp, dstp, fill, csr);

  for (int t = 0; t < TT; ++t) {
    k_gemm1<<<NN, 256, 0, stream>>>(x + (size_t)t * NN * FIN, W1, as1, ad1, h1, al1s, al1d);
    k_agg1<<<NN / 4, 256, 0, stream>>>(h1, al1s, al1d, rowptr, csr, b1, rel1);
    k_gemm2<<<NN / 8, 256, 0, stream>>>(rel1, W2, as2, ad2, h2, al2s, al2d);
    k_agg2<<<NN / 8, 256, 0, stream>>>(h2, al2s, al2d, rowptr, csr, b2, agg2);
    k_lstm<<<NN / (8 * LSTM_GRP), 256, 0, stream>>>(agg2, wih, whh, bih, bhh, hb, cb,
                                                    out + (size_t)t * NN * CD);
  }
  k_softmax<<<256, 256, 0, stream>>>(out);
}

// Round 2
// 1483.904 us; speedup vs baseline: 1.0348x; 1.0348x over previous
//
#include <hip/hip_runtime.h>
#include <math.h>

#define NN 20000   // nodes
#define NE 320000  // edges (without self-loops)
#define TT 8       // timesteps
#define D1 256     // H*F layer-1 width
#define CD 32      // layer-2 width == LSTM hidden

// ---------------- CSR build (once per launch; edges identical across t) ----------------

__global__ __launch_bounds__(256) void k_deg(const int* __restrict__ dst, int* __restrict__ deg) {
  int e = blockIdx.x * 256 + threadIdx.x;
  if (e < NE) atomicAdd(&deg[dst[e]], 1);
}

__global__ __launch_bounds__(1024) void k_scan(const int* __restrict__ deg,
                                               int* __restrict__ rowptr, int* __restrict__ fill) {
  __shared__ int sd[1024];
  __shared__ int carry_s;
  int tid = threadIdx.x;
  if (tid == 0) { carry_s = 0; rowptr[0] = 0; }
  __syncthreads();
  for (int base = 0; base < NN; base += 1024) {
    int i = base + tid;
    int v = (i < NN) ? deg[i] : 0;
    sd[tid] = v;
    __syncthreads();
    for (int off = 1; off < 1024; off <<= 1) {
      int t = (tid >= off) ? sd[tid - off] : 0;
      __syncthreads();
      sd[tid] += t;
      __syncthreads();
    }
    int incl = sd[tid];
    int carry = carry_s;
    if (i < NN) { rowptr[i + 1] = carry + incl; fill[i] = carry + incl - v; }
    __syncthreads();
    if (tid == 1023) carry_s = carry + sd[1023];
    __syncthreads();
  }
}

__global__ __launch_bounds__(256) void k_fill(const int* __restrict__ src, const int* __restrict__ dst,
                                              int* __restrict__ fill, int* __restrict__ csr) {
  int e = blockIdx.x * 256 + threadIdx.x;
  if (e < NE) {
    int pos = atomicAdd(&fill[dst[e]], 1);
    csr[pos] = src[e];
  }
}

// ---------------- GAT layer 1 GEMM: W1 column in VGPRs, x row broadcast from LDS ----------------
// thread j owns W1[:,j] (32 regs); block does 16 nodes.

__global__ __launch_bounds__(256) void k_gemm1(const float* __restrict__ x, const float* __restrict__ W1,
    const float* __restrict__ as1, const float* __restrict__ ad1,
    float* __restrict__ h1, float* __restrict__ als, float* __restrict__ ald) {
  int j = threadIdx.x;
  float w[32];
  #pragma unroll
  for (int k = 0; k < 32; ++k) w[k] = W1[k * D1 + j];
  float asj = as1[j], adj = ad1[j];
  __shared__ float xsh[16 * 32];
  int n0 = blockIdx.x * 16;
  for (int i = j; i < 512; i += 256) xsh[i] = x[n0 * 32 + i];
  __syncthreads();
  for (int g = 0; g < 16; ++g) {
    const float* xr = xsh + g * 32;
    float acc = 0.f;
    #pragma unroll
    for (int k = 0; k < 32; ++k) acc = fmaf(xr[k], w[k], acc);
    int n = n0 + g;
    h1[(size_t)n * D1 + j] = acc;
    float vs = acc * asj, vd = acc * adj;
    #pragma unroll
    for (int m = 1; m < 32; m <<= 1) {
      vs += __shfl_xor(vs, m, 64);
      vd += __shfl_xor(vd, m, 64);
    }
    if ((j & 31) == 0) {
      als[n * 8 + (j >> 5)] = vs;
      ald[n * 8 + (j >> 5)] = vd;
    }
  }
}

// ---------------- GAT layer 1 aggregation: wave per node, lane -> 4 features, 2-edge unroll ----

__global__ __launch_bounds__(256) void k_agg1(const float* __restrict__ h1,
    const float* __restrict__ als, const float* __restrict__ ald,
    const int* __restrict__ rowptr, const int* __restrict__ csr,
    const float* __restrict__ b1, float* __restrict__ out) {
  int lane = threadIdx.x & 63;
  int n = blockIdx.x * 4 + (threadIdx.x >> 6);
  int h = lane >> 3;
  float ad = ald[n * 8 + h];
  float4 acc = make_float4(0.f, 0.f, 0.f, 0.f);
  float den = 0.f;
  int beg = rowptr[n], end = rowptr[n + 1];
  int idx = beg;
  for (; idx + 2 <= end; idx += 2) {
    int s0 = csr[idx], s1 = csr[idx + 1];
    float a0 = als[s0 * 8 + h] + ad;
    float a1 = als[s1 * 8 + h] + ad;
    float4 v0 = *(const float4*)(h1 + (size_t)s0 * D1 + lane * 4);
    float4 v1 = *(const float4*)(h1 + (size_t)s1 * D1 + lane * 4);
    a0 = a0 > 0.f ? a0 : 0.2f * a0;
    a1 = a1 > 0.f ? a1 : 0.2f * a1;
    float e0 = __expf(a0), e1 = __expf(a1);
    acc.x = fmaf(e1, v1.x, fmaf(e0, v0.x, acc.x));
    acc.y = fmaf(e1, v1.y, fmaf(e0, v0.y, acc.y));
    acc.z = fmaf(e1, v1.z, fmaf(e0, v0.z, acc.z));
    acc.w = fmaf(e1, v1.w, fmaf(e0, v0.w, acc.w));
    den += e0 + e1;
  }
  for (; idx <= end; ++idx) {           // 0/1 leftover edges + self-loop
    int s = (idx < end) ? csr[idx] : n;
    float a = als[s * 8 + h] + ad;
    a = a > 0.f ? a : 0.2f * a;
    float e = __expf(a);
    float4 v = *(const float4*)(h1 + (size_t)s * D1 + lane * 4);
    acc.x = fmaf(e, v.x, acc.x);
    acc.y = fmaf(e, v.y, acc.y);
    acc.z = fmaf(e, v.z, acc.z);
    acc.w = fmaf(e, v.w, acc.w);
    den += e;
  }
  float inv = 1.f / den;
  int jj = lane * 4;
  float4 bb = *(const float4*)(b1 + jj);
  float4 o;
  o.x = fmaxf(fmaf(acc.x, inv, bb.x), 0.f);
  o.y = fmaxf(fmaf(acc.y, inv, bb.y), 0.f);
  o.z = fmaxf(fmaf(acc.z, inv, bb.z), 0.f);
  o.w = fmaxf(fmaf(acc.w, inv, bb.w), 0.f);
  *(float4*)(out + (size_t)n * D1 + jj) = o;
}

// ---------------- GAT layer 2 GEMM: W2 chunk in VGPRs, rel1 broadcast, k-split reduce --------
// 256 threads = 8 k-chunks x 32 cols; 32 nodes per block, 2 nodes per iteration.

__global__ __launch_bounds__(256) void k_gemm2(const float* __restrict__ rel1, const float* __restrict__ W2,
    const float* __restrict__ as2, const float* __restrict__ ad2,
    float* __restrict__ h2, float* __restrict__ als, float* __restrict__ ald) {
  __shared__ float rows[32 * D1];
  __shared__ float part[2][4][32];
  int tid = threadIdx.x;
  int q = tid >> 5, f = tid & 31;
  float w[32];
  #pragma unroll
  for (int jj = 0; jj < 32; ++jj) w[jj] = W2[(q * 32 + jj) * CD + f];
  int n0 = blockIdx.x * 32;
  for (int i = tid; i < 32 * D1; i += 256) rows[i] = rel1[(size_t)n0 * D1 + i];
  __syncthreads();
  int wv = tid >> 6;
  for (int g = 0; g < 16; ++g) {
    const float4* rA = (const float4*)(rows + (2 * g) * D1 + q * 32);
    const float4* rB = (const float4*)(rows + (2 * g + 1) * D1 + q * 32);
    float accA = 0.f, accB = 0.f;
    #pragma unroll
    for (int jj = 0; jj < 8; ++jj) {
      float4 a4 = rA[jj], b4 = rB[jj];
      accA = fmaf(a4.x, w[4 * jj], fmaf(a4.y, w[4 * jj + 1],
             fmaf(a4.z, w[4 * jj + 2], fmaf(a4.w, w[4 * jj + 3], accA))));
      accB = fmaf(b4.x, w[4 * jj], fmaf(b4.y, w[4 * jj + 1],
             fmaf(b4.z, w[4 * jj + 2], fmaf(b4.w, w[4 * jj + 3], accB))));
    }
    accA += __shfl_xor(accA, 32, 64);
    accB += __shfl_xor(accB, 32, 64);
    if ((tid & 32) == 0) { part[0][wv][f] = accA; part[1][wv][f] = accB; }
    __syncthreads();
    if (tid < 64) {
      int nn = tid >> 5, ff = tid & 31;
      float v = part[nn][0][ff] + part[nn][1][ff] + part[nn][2][ff] + part[nn][3][ff];
      int n = n0 + 2 * g + nn;
      h2[(size_t)n * CD + ff] = v;
      float vs = v * as2[ff], vd = v * ad2[ff];
      #pragma unroll
      for (int m = 1; m < 32; m <<= 1) {
        vs += __shfl_xor(vs, m, 64);
        vd += __shfl_xor(vd, m, 64);
      }
      if (ff == 0) { als[n] = vs; ald[n] = vd; }
    }
    __syncthreads();
  }
}

// ---------------- GAT layer 2 aggregation: 32 threads per node ----------------

__global__ __launch_bounds__(256) void k_agg2(const float* __restrict__ h2,
    const float* __restrict__ als, const float* __restrict__ ald,
    const int* __restrict__ rowptr, const int* __restrict__ csr,
    const float* __restrict__ b2, float* __restrict__ out) {
  int tid = threadIdx.x;
  int r = tid >> 5, f = tid & 31;
  int n = blockIdx.x * 8 + r;
  float ad = ald[n];
  float acc = 0.f, den = 0.f;
  int beg = rowptr[n], end = rowptr[n + 1];
  int idx = beg;
  for (; idx + 2 <= end; idx += 2) {
    int s0 = csr[idx], s1 = csr[idx + 1];
    float a0 = als[s0] + ad;
    float a1 = als[s1] + ad;
    float v0 = h2[(size_t)s0 * CD + f];
    float v1 = h2[(size_t)s1 * CD + f];
    a0 = a0 > 0.f ? a0 : 0.2f * a0;
    a1 = a1 > 0.f ? a1 : 0.2f * a1;
    float e0 = __expf(a0), e1 = __expf(a1);
    acc = fmaf(e1, v1, fmaf(e0, v0, acc));
    den += e0 + e1;
  }
  for (; idx <= end; ++idx) {
    int s = (idx < end) ? csr[idx] : n;
    float a = als[s] + ad;
    a = a > 0.f ? a : 0.2f * a;
    float e = __expf(a);
    acc = fmaf(e, h2[(size_t)s * CD + f], acc);
    den += e;
  }
  out[(size_t)n * CD + f] = acc / den + b2[f];
}

// ---------------- LSTM step: gate-packed float4 weights in LDS, 2 nodes per thread ----------

__global__ __launch_bounds__(256) void k_lstm(const float* __restrict__ xt,
    const float* __restrict__ w_ih, const float* __restrict__ w_hh,
    const float* __restrict__ b_ih, const float* __restrict__ b_hh,
    float* __restrict__ h, float* __restrict__ c, float* __restrict__ out_t) {
  __shared__ float4 wi4[32 * 32];  // [j][k] = gates (i,f,g,o) of w_ih[:,j] at row k
  __shared__ float4 wh4[32 * 32];
  __shared__ float xs[512], hs[512];
  int tid = threadIdx.x;
  for (int i = tid; i < 1024; i += 256) {
    int k = i >> 5, j = i & 31;
    wi4[j * 32 + k] = make_float4(w_ih[k * 32 + j], w_ih[(32 + k) * 32 + j],
                                  w_ih[(64 + k) * 32 + j], w_ih[(96 + k) * 32 + j]);
    wh4[j * 32 + k] = make_float4(w_hh[k * 32 + j], w_hh[(32 + k) * 32 + j],
                                  w_hh[(64 + k) * 32 + j], w_hh[(96 + k) * 32 + j]);
  }
  int r = tid >> 5;   // 0..7
  int k = tid & 31;
  float bi = b_ih[k] + b_hh[k];
  float bf = b_ih[32 + k] + b_hh[32 + k];
  float bg = b_ih[64 + k] + b_hh[64 + k];
  float bo = b_ih[96 + k] + b_hh[96 + k];
  for (int it = 0; it < 2; ++it) {
    int base = blockIdx.x * 32 + it * 16;  // 16 nodes this iteration
    __syncthreads();
    for (int i = tid; i < 512; i += 256) {
      xs[i] = xt[base * 32 + i];
      hs[i] = h[base * 32 + i];
    }
    __syncthreads();
    float aiA = bi, afA = bf, agA = bg, aoA = bo;
    float aiB = bi, afB = bf, agB = bg, aoB = bo;
    const float* xA = xs + r * 32;
    const float* xB = xs + (r + 8) * 32;
    const float* hA = hs + r * 32;
    const float* hB = hs + (r + 8) * 32;
    #pragma unroll
    for (int j = 0; j < 32; ++j) {
      float4 wi = wi4[j * 32 + k], wh = wh4[j * 32 + k];
      float xa = xA[j], ha = hA[j], xb = xB[j], hb = hB[j];
      aiA = fmaf(xa, wi.x, fmaf(ha, wh.x, aiA));
      afA = fmaf(xa, wi.y, fmaf(ha, wh.y, afA));
      agA = fmaf(xa, wi.z, fmaf(ha, wh.z, agA));
      aoA = fmaf(xa, wi.w, fmaf(ha, wh.w, aoA));
      aiB = fmaf(xb, wi.x, fmaf(hb, wh.x, aiB));
      afB = fmaf(xb, wi.y, fmaf(hb, wh.y, afB));
      agB = fmaf(xb, wi.z, fmaf(hb, wh.z, agB));
      aoB = fmaf(xb, wi.w, fmaf(hb, wh.w, aoB));
    }
    int gA = (base + r) * 32 + k;
    int gB = (base + r + 8) * 32 + k;
    float iiA = 1.f / (1.f + __expf(-aiA));
    float ffA = 1.f / (1.f + __expf(-afA));
    float ggA = tanhf(agA);
    float ooA = 1.f / (1.f + __expf(-aoA));
    float cA = fmaf(ffA, c[gA], iiA * ggA);
    float hnA = ooA * tanhf(cA);
    c[gA] = cA; h[gA] = hnA; out_t[gA] = hnA;
    float iiB = 1.f / (1.f + __expf(-aiB));
    float ffB = 1.f / (1.f + __expf(-afB));
    float ggB = tanhf(agB);
    float ooB = 1.f / (1.f + __expf(-aoB));
    float cB = fmaf(ffB, c[gB], iiB * ggB);
    float hnB = ooB * tanhf(cB);
    c[gB] = cB; h[gB] = hnB; out_t[gB] = hnB;
  }
}

// ---------------- softmax over nodes, coalesced two-pass ----------------
// grid (25, 8): block covers 800 nodes x 32 ch of one t.

__global__ __launch_bounds__(256) void k_sm_sum(const float* __restrict__ out, float* __restrict__ sums) {
  int t = blockIdx.y;
  const float4* b4 = (const float4*)(out + ((size_t)t * NN + blockIdx.x * 800) * CD);
  int tid = threadIdx.x;
  float4 s4 = make_float4(0.f, 0.f, 0.f, 0.f);
  for (int i = tid; i < 6400; i += 256) {
    float4 v = b4[i];
    s4.x += __expf(v.x); s4.y += __expf(v.y);
    s4.z += __expf(v.z); s4.w += __expf(v.w);
  }
  __shared__ float4 red[256];
  red[tid] = s4;
  __syncthreads();
  for (int off = 128; off >= 8; off >>= 1) {
    if (tid < off) {
      float4 o = red[tid + off];
      red[tid].x += o.x; red[tid].y += o.y; red[tid].z += o.z; red[tid].w += o.w;
    }
    __syncthreads();
  }
  if (tid < 8) {
    float4 v = red[tid];
    int c0 = tid * 4;
    atomicAdd(&sums[t * CD + c0 + 0], v.x);
    atomicAdd(&sums[t * CD + c0 + 1], v.y);
    atomicAdd(&sums[t * CD + c0 + 2], v.z);
    atomicAdd(&sums[t * CD + c0 + 3], v.w);
  }
}

__global__ __launch_bounds__(256) void k_sm_scale(float* __restrict__ out, const float* __restrict__ sums) {
  int t = blockIdx.y;
  __shared__ float inv[CD];
  int tid = threadIdx.x;
  if (tid < CD) inv[tid] = 1.f / sums[t * CD + tid];
  __syncthreads();
  float4* b4 = (float4*)(out + ((size_t)t * NN + blockIdx.x * 800) * CD);
  for (int i = tid; i < 6400; i += 256) {
    float4 v = b4[i];
    int c0 = (4 * i) & 31;
    v.x = __expf(v.x) * inv[c0];
    v.y = __expf(v.y) * inv[c0 + 1];
    v.z = __expf(v.z) * inv[c0 + 2];
    v.w = __expf(v.w) * inv[c0 + 3];
    b4[i] = v;
  }
}

// ---------------- launch ----------------

extern "C" void kernel_launch(void* const* d_in, const int* in_sizes, int n_in,
                              void* d_out, int out_size, void* d_ws, size_t ws_size,
                              hipStream_t stream) {
  const float* x   = (const float*)d_in[0];
  const float* W1  = (const float*)d_in[1];
  const float* as1 = (const float*)d_in[2];
  const float* ad1 = (const float*)d_in[3];
  const float* b1  = (const float*)d_in[4];
  const float* W2  = (const float*)d_in[5];
  const float* as2 = (const float*)d_in[6];
  const float* ad2 = (const float*)d_in[7];
  const float* b2  = (const float*)d_in[8];
  const float* wih = (const float*)d_in[9];
  const float* whh = (const float*)d_in[10];
  const float* bih = (const float*)d_in[11];
  const float* bhh = (const float*)d_in[12];
  const int*   ei  = (const int*)d_in[13];
  const int* srcp = ei;
  const int* dstp = ei + NE;
  float* out = (float*)d_out;

  float* ws = (float*)d_ws;
  float* h1    = ws;  ws += (size_t)NN * D1;
  float* rel1  = ws;  ws += (size_t)NN * D1;
  float* al1s  = ws;  ws += NN * 8;
  float* al1d  = ws;  ws += NN * 8;
  float* h2    = ws;  ws += NN * CD;
  float* al2s  = ws;  ws += NN;
  float* al2d  = ws;  ws += NN;
  float* agg2o = ws;  ws += NN * CD;
  float* hb    = ws;  ws += NN * CD;   // hb, cb, sums contiguous -> one memset
  float* cb    = ws;  ws += NN * CD;
  float* sums  = ws;  ws += TT * CD;
  int* rowptr = (int*)ws;
  int* fill   = rowptr + NN + 1;
  int* csr    = fill + NN;
  int* deg    = csr + NE;

  hipMemsetAsync(deg, 0, NN * sizeof(int), stream);
  hipMemsetAsync(hb, 0, (2 * NN * CD + TT * CD) * sizeof(float), stream);

  k_deg<<<(NE + 255) / 256, 256, 0, stream>>>(dstp, deg);
  k_scan<<<1, 1024, 0, stream>>>(deg, rowptr, fill);
  k_fill<<<(NE + 255) / 256, 256, 0, stream>>>(srcp, dstp, fill, csr);

  for (int t = 0; t < TT; ++t) {
    const float* xt = x + (size_t)t * NN * 32;
    k_gemm1<<<NN / 16, 256, 0, stream>>>(xt, W1, as1, ad1, h1, al1s, al1d);
    k_agg1<<<NN / 4, 256, 0, stream>>>(h1, al1s, al1d, rowptr, csr, b1, rel1);
    k_gemm2<<<NN / 32, 256, 0, stream>>>(rel1, W2, as2, ad2, h2, al2s, al2d);
    k_agg2<<<NN / 8, 256, 0, stream>>>(h2, al2s, al2d, rowptr, csr, b2, agg2o);
    k_lstm<<<NN / 32, 256, 0, stream>>>(agg2o, wih, whh, bih, bhh, hb, cb,
                                        out + (size_t)t * NN * CD);
  }
  k_sm_sum<<<dim3(25, TT), 256, 0, stream>>>(out, sums);
  k_sm_scale<<<dim3(25, TT), 256, 0, stream>>>(out, sums);
}

// Round 3
// 973.738 us; speedup vs baseline: 1.5770x; 1.5239x over previous
//
#include <hip/hip_runtime.h>
#include <math.h>

#define NN 20000   // nodes
#define NE 320000  // edges (without self-loops)
#define TT 8       // timesteps
#define D1 256     // H*F layer-1 width
#define CD 32      // layer-2 width == LSTM hidden

// ---------------- CSR build (once per launch; edges identical across t) ----------------

__global__ __launch_bounds__(256) void k_deg(const int* __restrict__ dst, int* __restrict__ deg) {
  int e = blockIdx.x * 256 + threadIdx.x;
  if (e < NE) atomicAdd(&deg[dst[e]], 1);
}

__global__ __launch_bounds__(1024) void k_scan(const int* __restrict__ deg,
                                               int* __restrict__ rowptr, int* __restrict__ fill) {
  __shared__ int sd[1024];
  __shared__ int carry_s;
  int tid = threadIdx.x;
  if (tid == 0) { carry_s = 0; rowptr[0] = 0; }
  __syncthreads();
  for (int base = 0; base < NN; base += 1024) {
    int i = base + tid;
    int v = (i < NN) ? deg[i] : 0;
    sd[tid] = v;
    __syncthreads();
    for (int off = 1; off < 1024; off <<= 1) {
      int t = (tid >= off) ? sd[tid - off] : 0;
      __syncthreads();
      sd[tid] += t;
      __syncthreads();
    }
    int incl = sd[tid];
    int carry = carry_s;
    if (i < NN) { rowptr[i + 1] = carry + incl; fill[i] = carry + incl - v; }
    __syncthreads();
    if (tid == 1023) carry_s = carry + sd[1023];
    __syncthreads();
  }
}

__global__ __launch_bounds__(256) void k_fill(const int* __restrict__ src, const int* __restrict__ dst,
                                              int* __restrict__ fill, int* __restrict__ csr) {
  int e = blockIdx.x * 256 + threadIdx.x;
  if (e < NE) {
    int pos = atomicAdd(&fill[dst[e]], 1);
    csr[pos] = src[e];
  }
}

// ---------------- one-time: w~src[k][h] = sum_f W1[k, h*32+f] * a_src[h][f] ----------------

__global__ __launch_bounds__(256) void k_prew(const float* __restrict__ W1,
    const float* __restrict__ as1, const float* __restrict__ ad1,
    float* __restrict__ wsrc, float* __restrict__ wdst) {
  int tid = threadIdx.x;
  int k = tid >> 3, h = tid & 7;
  float s = 0.f, d = 0.f;
  #pragma unroll
  for (int f = 0; f < 32; ++f) {
    float wv = W1[k * D1 + h * 32 + f];
    s = fmaf(wv, as1[h * 32 + f], s);
    d = fmaf(wv, ad1[h * 32 + f], d);
  }
  wsrc[k * 8 + h] = s;
  wdst[k * 8 + h] = d;
}

// ---------------- per-t logits: als/ald = x @ w~ ; 32 nodes x 8 heads per block ------------

__global__ __launch_bounds__(256) void k_logits(const float* __restrict__ xt,
    const float* __restrict__ wsrc, const float* __restrict__ wdst,
    float* __restrict__ als, float* __restrict__ ald) {
  __shared__ float xs[32 * 33];
  __shared__ float wsr[256], wdr[256];
  int tid = threadIdx.x;
  int nl = tid >> 3, h = tid & 7;
  int n0 = blockIdx.x * 32;
  for (int i = tid; i < 1024; i += 256) {
    int g = i >> 5, k = i & 31;
    xs[g * 33 + k] = xt[n0 * 32 + i];
  }
  wsr[tid] = wsrc[tid];
  wdr[tid] = wdst[tid];
  __syncthreads();
  const float* xr = xs + nl * 33;
  float as = 0.f, ad = 0.f;
  #pragma unroll
  for (int k = 0; k < 32; ++k) {
    float xv = xr[k];
    as = fmaf(xv, wsr[k * 8 + h], as);
    ad = fmaf(xv, wdr[k * 8 + h], ad);
  }
  als[n0 * 8 + tid] = as;
  ald[n0 * 8 + tid] = ad;
}

// ---------------- layer-1 aggregation in x-space: gather 128B x rows (L2-resident) ---------
// wave per node; lane = h*8+fb accumulates aggx[n][h][fb*4..+3] = sum_e e_h * x[s][fb*4..+3]

__global__ __launch_bounds__(256) void k_agg1x(const float* __restrict__ xt,
    const float* __restrict__ als, const float* __restrict__ ald,
    const int* __restrict__ rowptr, const int* __restrict__ csr,
    float* __restrict__ aggx, float* __restrict__ den1) {
  int lane = threadIdx.x & 63;
  int n = blockIdx.x * 4 + (threadIdx.x >> 6);
  int h = lane >> 3, fb = lane & 7;
  float ad = ald[n * 8 + h];
  const float4* x4 = (const float4*)xt;
  float4 acc = make_float4(0.f, 0.f, 0.f, 0.f);
  float den = 0.f;
  int beg = rowptr[n], end = rowptr[n + 1];
  int idx = beg;
  for (; idx + 2 <= end; idx += 2) {
    int s0 = csr[idx], s1 = csr[idx + 1];
    float a0 = als[s0 * 8 + h] + ad;
    float a1 = als[s1 * 8 + h] + ad;
    float4 v0 = x4[s0 * 8 + fb];
    float4 v1 = x4[s1 * 8 + fb];
    a0 = a0 > 0.f ? a0 : 0.2f * a0;
    a1 = a1 > 0.f ? a1 : 0.2f * a1;
    float e0 = __expf(a0), e1 = __expf(a1);
    acc.x = fmaf(e1, v1.x, fmaf(e0, v0.x, acc.x));
    acc.y = fmaf(e1, v1.y, fmaf(e0, v0.y, acc.y));
    acc.z = fmaf(e1, v1.z, fmaf(e0, v0.z, acc.z));
    acc.w = fmaf(e1, v1.w, fmaf(e0, v0.w, acc.w));
    den += e0 + e1;
  }
  for (; idx <= end; ++idx) {             // leftover edge + self-loop
    int s = (idx < end) ? csr[idx] : n;
    float a = als[s * 8 + h] + ad;
    a = a > 0.f ? a : 0.2f * a;
    float e = __expf(a);
    float4 v = x4[s * 8 + fb];
    acc.x = fmaf(e, v.x, acc.x);
    acc.y = fmaf(e, v.y, acc.y);
    acc.z = fmaf(e, v.z, acc.z);
    acc.w = fmaf(e, v.w, acc.w);
    den += e;
  }
  *(float4*)(aggx + (size_t)n * D1 + lane * 4) = acc;
  if (fb == 0) den1[n * 8 + h] = den;
}

// ---------------- layer-1 epilogue: rel1 = relu(aggx @ W1_headblock / den + b1) -------------
// thread j owns W1[:,j] in 32 VGPRs; 16 nodes per block, aggx broadcast from padded LDS.

__global__ __launch_bounds__(256) void k_post1(const float* __restrict__ aggx,
    const float* __restrict__ den1, const float* __restrict__ W1,
    const float* __restrict__ b1, float* __restrict__ rel1) {
  __shared__ float aggs[16 * 264];   // g*264 + h*33 + k  (padded: bank = h+k+8g)
  __shared__ float dens[16 * 8];
  int j = threadIdx.x;
  int h = j >> 5;
  float w[32];
  #pragma unroll
  for (int k = 0; k < 32; ++k) w[k] = W1[k * D1 + j];
  float bj = b1[j];
  int n0 = blockIdx.x * 16;
  for (int i = j; i < 4096; i += 256) {
    int g = i >> 8, rem = i & 255;
    aggs[g * 264 + (rem >> 5) * 33 + (rem & 31)] = aggx[(size_t)n0 * D1 + i];
  }
  if (j < 128) dens[j] = den1[n0 * 8 + j];
  __syncthreads();
  for (int g = 0; g < 16; ++g) {
    const float* ar = aggs + g * 264 + h * 33;
    float acc = 0.f;
    #pragma unroll
    for (int k = 0; k < 32; ++k) acc = fmaf(ar[k], w[k], acc);
    float v = fmaf(acc, 1.f / dens[g * 8 + h], bj);
    rel1[(size_t)(n0 + g) * D1 + j] = fmaxf(v, 0.f);
  }
}

// ---------------- GAT layer 2 GEMM: 8-node supergroups, 8 barriers/block --------------------

__global__ __launch_bounds__(256) void k_gemm2(const float* __restrict__ rel1, const float* __restrict__ W2,
    const float* __restrict__ as2, const float* __restrict__ ad2,
    float* __restrict__ h2, float* __restrict__ als, float* __restrict__ ald) {
  __shared__ float rows[32 * D1];
  __shared__ float part[4][8][32];
  int tid = threadIdx.x;
  int q = tid >> 5, f = tid & 31;
  float w[32];
  #pragma unroll
  for (int jj = 0; jj < 32; ++jj) w[jj] = W2[(q * 32 + jj) * CD + f];
  int n0 = blockIdx.x * 32;
  for (int i = tid; i < 32 * D1; i += 256) rows[i] = rel1[(size_t)n0 * D1 + i];
  __syncthreads();
  int wv = tid >> 6;
  for (int sg = 0; sg < 4; ++sg) {
    float acc[8];
    #pragma unroll
    for (int nn = 0; nn < 8; ++nn) {
      const float4* r4 = (const float4*)(rows + (sg * 8 + nn) * D1 + q * 32);
      float a = 0.f;
      #pragma unroll
      for (int jj = 0; jj < 8; ++jj) {
        float4 a4 = r4[jj];
        a = fmaf(a4.x, w[4 * jj], fmaf(a4.y, w[4 * jj + 1],
            fmaf(a4.z, w[4 * jj + 2], fmaf(a4.w, w[4 * jj + 3], a))));
      }
      acc[nn] = a + __shfl_xor(a, 32, 64);
    }
    if ((tid & 32) == 0) {
      #pragma unroll
      for (int nn = 0; nn < 8; ++nn) part[wv][nn][f] = acc[nn];
    }
    __syncthreads();
    {
      int nl = tid >> 5, ff = tid & 31;
      float v = part[0][nl][ff] + part[1][nl][ff] + part[2][nl][ff] + part[3][nl][ff];
      int n = n0 + sg * 8 + nl;
      h2[(size_t)n * CD + ff] = v;
      float vs = v * as2[ff], vd = v * ad2[ff];
      #pragma unroll
      for (int m = 1; m < 32; m <<= 1) {
        vs += __shfl_xor(vs, m, 64);
        vd += __shfl_xor(vd, m, 64);
      }
      if (ff == 0) { als[n] = vs; ald[n] = vd; }
    }
    __syncthreads();
  }
}

// ---------------- GAT layer 2 aggregation: 32 threads per node (h2 is L2-resident) ----------

__global__ __launch_bounds__(256) void k_agg2(const float* __restrict__ h2,
    const float* __restrict__ als, const float* __restrict__ ald,
    const int* __restrict__ rowptr, const int* __restrict__ csr,
    const float* __restrict__ b2, float* __restrict__ out) {
  int tid = threadIdx.x;
  int r = tid >> 5, f = tid & 31;
  int n = blockIdx.x * 8 + r;
  float ad = ald[n];
  float acc = 0.f, den = 0.f;
  int beg = rowptr[n], end = rowptr[n + 1];
  int idx = beg;
  for (; idx + 2 <= end; idx += 2) {
    int s0 = csr[idx], s1 = csr[idx + 1];
    float a0 = als[s0] + ad;
    float a1 = als[s1] + ad;
    float v0 = h2[(size_t)s0 * CD + f];
    float v1 = h2[(size_t)s1 * CD + f];
    a0 = a0 > 0.f ? a0 : 0.2f * a0;
    a1 = a1 > 0.f ? a1 : 0.2f * a1;
    float e0 = __expf(a0), e1 = __expf(a1);
    acc = fmaf(e1, v1, fmaf(e0, v0, acc));
    den += e0 + e1;
  }
  for (; idx <= end; ++idx) {
    int s = (idx < end) ? csr[idx] : n;
    float a = als[s] + ad;
    a = a > 0.f ? a : 0.2f * a;
    float e = __expf(a);
    acc = fmaf(e, h2[(size_t)s * CD + f], acc);
    den += e;
  }
  out[(size_t)n * CD + f] = acc / den + b2[f];
}

// ---------------- LSTM: gate-row weights in VGPRs, activations broadcast via LDS ------------
// thread = (slot 0/1, gate-row r 0..127); 32 nodes/block in 2 iters of 16.

__global__ __launch_bounds__(256) void k_lstm(const float* __restrict__ xt,
    const float* __restrict__ w_ih, const float* __restrict__ w_hh,
    const float* __restrict__ b_ih, const float* __restrict__ b_hh,
    float* __restrict__ h, float* __restrict__ c, float* __restrict__ out_t) {
  __shared__ float xs[16 * 32], hs[16 * 32], pre[16 * 128];
  int tid = threadIdx.x;
  int slot = tid >> 7;
  int r = tid & 127;
  float4 wi[8], wh[8];
  const float4* wi4 = (const float4*)(w_ih + r * 32);
  const float4* wh4 = (const float4*)(w_hh + r * 32);
  #pragma unroll
  for (int q = 0; q < 8; ++q) { wi[q] = wi4[q]; wh[q] = wh4[q]; }
  float bias = b_ih[r] + b_hh[r];
  for (int it = 0; it < 2; ++it) {
    int base = blockIdx.x * 32 + it * 16;
    __syncthreads();                       // guard xs/hs/pre reuse
    for (int i = tid; i < 512; i += 256) {
      xs[i] = xt[base * 32 + i];
      hs[i] = h[base * 32 + i];
    }
    __syncthreads();
    #pragma unroll
    for (int g = 0; g < 8; ++g) {
      int nl = slot * 8 + g;
      const float4* xv4 = (const float4*)(xs + nl * 32);
      const float4* hv4 = (const float4*)(hs + nl * 32);
      float acc = bias;
      #pragma unroll
      for (int q = 0; q < 8; ++q) {
        float4 a = xv4[q], b = hv4[q];
        acc = fmaf(a.x, wi[q].x, acc);
        acc = fmaf(a.y, wi[q].y, acc);
        acc = fmaf(a.z, wi[q].z, acc);
        acc = fmaf(a.w, wi[q].w, acc);
        acc = fmaf(b.x, wh[q].x, acc);
        acc = fmaf(b.y, wh[q].y, acc);
        acc = fmaf(b.z, wh[q].z, acc);
        acc = fmaf(b.w, wh[q].w, acc);
      }
      pre[nl * 128 + r] = acc;
    }
    __syncthreads();
    for (int i = tid; i < 512; i += 256) {
      int nl = i >> 5, k = i & 31;
      float ai = pre[nl * 128 + k];
      float af = pre[nl * 128 + 32 + k];
      float ag = pre[nl * 128 + 64 + k];
      float ao = pre[nl * 128 + 96 + k];
      float ii = 1.f / (1.f + __expf(-ai));
      float ff = 1.f / (1.f + __expf(-af));
      float gg = tanhf(ag);
      float oo = 1.f / (1.f + __expf(-ao));
      int gi = (base + nl) * 32 + k;
      float cn = fmaf(ff, c[gi], ii * gg);
      float hn = oo * tanhf(cn);
      c[gi] = cn; h[gi] = hn; out_t[gi] = hn;
    }
  }
}

// ---------------- softmax over nodes, coalesced two-pass ----------------

__global__ __launch_bounds__(256) void k_sm_sum(const float* __restrict__ out, float* __restrict__ sums) {
  int t = blockIdx.y;
  const float4* b4 = (const float4*)(out + ((size_t)t * NN + blockIdx.x * 800) * CD);
  int tid = threadIdx.x;
  float4 s4 = make_float4(0.f, 0.f, 0.f, 0.f);
  for (int i = tid; i < 6400; i += 256) {
    float4 v = b4[i];
    s4.x += __expf(v.x); s4.y += __expf(v.y);
    s4.z += __expf(v.z); s4.w += __expf(v.w);
  }
  __shared__ float4 red[256];
  red[tid] = s4;
  __syncthreads();
  for (int off = 128; off >= 8; off >>= 1) {
    if (tid < off) {
      float4 o = red[tid + off];
      red[tid].x += o.x; red[tid].y += o.y; red[tid].z += o.z; red[tid].w += o.w;
    }
    __syncthreads();
  }
  if (tid < 8) {
    float4 v = red[tid];
    int c0 = tid * 4;
    atomicAdd(&sums[t * CD + c0 + 0], v.x);
    atomicAdd(&sums[t * CD + c0 + 1], v.y);
    atomicAdd(&sums[t * CD + c0 + 2], v.z);
    atomicAdd(&sums[t * CD + c0 + 3], v.w);
  }
}

__global__ __launch_bounds__(256) void k_sm_scale(float* __restrict__ out, const float* __restrict__ sums) {
  int t = blockIdx.y;
  __shared__ float inv[CD];
  int tid = threadIdx.x;
  if (tid < CD) inv[tid] = 1.f / sums[t * CD + tid];
  __syncthreads();
  float4* b4 = (float4*)(out + ((size_t)t * NN + blockIdx.x * 800) * CD);
  for (int i = tid; i < 6400; i += 256) {
    float4 v = b4[i];
    int c0 = (4 * i) & 31;
    v.x = __expf(v.x) * inv[c0];
    v.y = __expf(v.y) * inv[c0 + 1];
    v.z = __expf(v.z) * inv[c0 + 2];
    v.w = __expf(v.w) * inv[c0 + 3];
    b4[i] = v;
  }
}

// ---------------- launch ----------------

extern "C" void kernel_launch(void* const* d_in, const int* in_sizes, int n_in,
                              void* d_out, int out_size, void* d_ws, size_t ws_size,
                              hipStream_t stream) {
  const float* x   = (const float*)d_in[0];
  const float* W1  = (const float*)d_in[1];
  const float* as1 = (const float*)d_in[2];
  const float* ad1 = (const float*)d_in[3];
  const float* b1  = (const float*)d_in[4];
  const float* W2  = (const float*)d_in[5];
  const float* as2 = (const float*)d_in[6];
  const float* ad2 = (const float*)d_in[7];
  const float* b2  = (const float*)d_in[8];
  const float* wih = (const float*)d_in[9];
  const float* whh = (const float*)d_in[10];
  const float* bih = (const float*)d_in[11];
  const float* bhh = (const float*)d_in[12];
  const int*   ei  = (const int*)d_in[13];
  const int* srcp = ei;
  const int* dstp = ei + NE;
  float* out = (float*)d_out;

  float* ws = (float*)d_ws;
  float* aggx  = ws;  ws += (size_t)NN * D1;
  float* rel1  = ws;  ws += (size_t)NN * D1;
  float* al1s  = ws;  ws += NN * 8;
  float* al1d  = ws;  ws += NN * 8;
  float* den1  = ws;  ws += NN * 8;
  float* h2    = ws;  ws += NN * CD;
  float* al2s  = ws;  ws += NN;
  float* al2d  = ws;  ws += NN;
  float* agg2o = ws;  ws += NN * CD;
  float* hb    = ws;  ws += NN * CD;   // hb, cb, sums contiguous -> one memset
  float* cb    = ws;  ws += NN * CD;
  float* sums  = ws;  ws += TT * CD;
  float* wsrc  = ws;  ws += 256;
  float* wdst  = ws;  ws += 256;
  int* rowptr = (int*)ws;
  int* fill   = rowptr + NN + 1;
  int* csr    = fill + NN;
  int* deg    = csr + NE;

  hipMemsetAsync(deg, 0, NN * sizeof(int), stream);
  hipMemsetAsync(hb, 0, (2 * NN * CD + TT * CD) * sizeof(float), stream);

  k_deg<<<(NE + 255) / 256, 256, 0, stream>>>(dstp, deg);
  k_scan<<<1, 1024, 0, stream>>>(deg, rowptr, fill);
  k_fill<<<(NE + 255) / 256, 256, 0, stream>>>(srcp, dstp, fill, csr);
  k_prew<<<1, 256, 0, stream>>>(W1, as1, ad1, wsrc, wdst);

  for (int t = 0; t < TT; ++t) {
    const float* xt = x + (size_t)t * NN * 32;
    k_logits<<<NN / 32, 256, 0, stream>>>(xt, wsrc, wdst, al1s, al1d);
    k_agg1x<<<NN / 4, 256, 0, stream>>>(xt, al1s, al1d, rowptr, csr, aggx, den1);
    k_post1<<<NN / 16, 256, 0, stream>>>(aggx, den1, W1, b1, rel1);
    k_gemm2<<<NN / 32, 256, 0, stream>>>(rel1, W2, as2, ad2, h2, al2s, al2d);
    k_agg2<<<NN / 8, 256, 0, stream>>>(h2, al2s, al2d, rowptr, csr, b2, agg2o);
    k_lstm<<<NN / 32, 256, 0, stream>>>(agg2o, wih, whh, bih, bhh, hb, cb,
                                        out + (size_t)t * NN * CD);
  }
  k_sm_sum<<<dim3(25, TT), 256, 0, stream>>>(out, sums);
  k_sm_scale<<<dim3(25, TT), 256, 0, stream>>>(out, sums);
}

// Round 4
// 663.103 us; speedup vs baseline: 2.3157x; 1.4685x over previous
//
#include <hip/hip_runtime.h>
#include <math.h>

#define NN 20000   // nodes
#define NE 320000  // edges (without self-loops)
#define TT 8       // timesteps
#define D1 256     // H*F layer-1 width
#define CD 32      // layer-2 width == LSTM hidden

// ---------------- CSR build (once per launch; edges identical across t) ----------------

__global__ __launch_bounds__(256) void k_deg(const int* __restrict__ dst, int* __restrict__ deg) {
  int e = blockIdx.x * 256 + threadIdx.x;
  if (e < NE) atomicAdd(&deg[dst[e]], 1);
}

__global__ __launch_bounds__(1024) void k_scan(const int* __restrict__ deg,
                                               int* __restrict__ rowptr, int* __restrict__ fill) {
  __shared__ int sd[1024];
  __shared__ int carry_s;
  int tid = threadIdx.x;
  if (tid == 0) { carry_s = 0; rowptr[0] = 0; }
  __syncthreads();
  for (int base = 0; base < NN; base += 1024) {
    int i = base + tid;
    int v = (i < NN) ? deg[i] : 0;
    sd[tid] = v;
    __syncthreads();
    for (int off = 1; off < 1024; off <<= 1) {
      int t = (tid >= off) ? sd[tid - off] : 0;
      __syncthreads();
      sd[tid] += t;
      __syncthreads();
    }
    int incl = sd[tid];
    int carry = carry_s;
    if (i < NN) { rowptr[i + 1] = carry + incl; fill[i] = carry + incl - v; }
    __syncthreads();
    if (tid == 1023) carry_s = carry + sd[1023];
    __syncthreads();
  }
}

__global__ __launch_bounds__(256) void k_fill(const int* __restrict__ src, const int* __restrict__ dst,
                                              int* __restrict__ fill, int* __restrict__ csr) {
  int e = blockIdx.x * 256 + threadIdx.x;
  if (e < NE) {
    int pos = atomicAdd(&fill[dst[e]], 1);
    csr[pos] = src[e];
  }
}

// ---------------- one-time: w~src[k][h] = sum_f W1[k, h*32+f] * a_src[h][f] ----------------

__global__ __launch_bounds__(256) void k_prew(const float* __restrict__ W1,
    const float* __restrict__ as1, const float* __restrict__ ad1,
    float* __restrict__ wsrc, float* __restrict__ wdst) {
  int tid = threadIdx.x;
  int k = tid >> 3, h = tid & 7;
  float s = 0.f, d = 0.f;
  #pragma unroll
  for (int f = 0; f < 32; ++f) {
    float wv = W1[k * D1 + h * 32 + f];
    s = fmaf(wv, as1[h * 32 + f], s);
    d = fmaf(wv, ad1[h * 32 + f], d);
  }
  wsrc[k * 8 + h] = s;
  wdst[k * 8 + h] = d;
}

// ---------------- logits for all t: als/ald = x @ w~ ; t = blockIdx.x & 7 -------------------

__global__ __launch_bounds__(256) void k_logits8(const float* __restrict__ x,
    const float* __restrict__ wsrc, const float* __restrict__ wdst,
    float* __restrict__ als, float* __restrict__ ald) {
  __shared__ float xs[32 * 33];
  __shared__ float wsr[256], wdr[256];
  int tid = threadIdx.x;
  int t = blockIdx.x & 7;
  int n0 = (blockIdx.x >> 3) * 32;
  const float* xt = x + (size_t)t * NN * 32;
  int nl = tid >> 3, h = tid & 7;
  for (int i = tid; i < 1024; i += 256) {
    int g = i >> 5, k = i & 31;
    xs[g * 33 + k] = xt[n0 * 32 + i];
  }
  wsr[tid] = wsrc[tid];
  wdr[tid] = wdst[tid];
  __syncthreads();
  const float* xr = xs + nl * 33;
  float as = 0.f, ad = 0.f;
  #pragma unroll
  for (int k = 0; k < 32; ++k) {
    float xv = xr[k];
    as = fmaf(xv, wsr[k * 8 + h], as);
    ad = fmaf(xv, wdr[k * 8 + h], ad);
  }
  als[(size_t)t * NN * 8 + n0 * 8 + tid] = as;
  ald[(size_t)t * NN * 8 + n0 * 8 + tid] = ad;
}

// ---------------- fused layer-1 gather + post1 GEMM + layer-2 GEMM, all t -------------------
// block: 4 nodes (one per wave) of one t. Gather x rows in x-space, project through W1
// (cols in VGPRs), relu, then W2 (cols in VGPRs) -> h2 + layer-2 logits. All LDS reads
// in the GEMM phases are wave-broadcast (conflict-free).

__global__ __launch_bounds__(256) void k_fused8(const float* __restrict__ x,
    const float* __restrict__ W1, const float* __restrict__ b1,
    const float* __restrict__ W2, const float* __restrict__ as2, const float* __restrict__ ad2,
    const float* __restrict__ als, const float* __restrict__ ald,
    const int* __restrict__ rowptr, const int* __restrict__ csr,
    float* __restrict__ h2, float* __restrict__ al2s, float* __restrict__ al2d) {
  __shared__ float aggs[4 * 256];
  __shared__ float dens[4 * 8];
  __shared__ float rels[4 * 256];
  __shared__ float part[4][4][32];
  int tid = threadIdx.x;
  int t = blockIdx.x & 7;
  int n0 = (blockIdx.x >> 3) * 4;
  const float* xt = x + (size_t)t * NN * 32;
  const float* alst = als + (size_t)t * NN * 8;
  const float* aldt = ald + (size_t)t * NN * 8;

  // per-thread weight columns (held in VGPRs through all phases)
  int j = tid;
  float w1c[32];
  #pragma unroll
  for (int k = 0; k < 32; ++k) w1c[k] = W1[k * D1 + j];
  float bj = b1[j];
  int q = tid >> 5, f = tid & 31;
  float w2c[32];
  #pragma unroll
  for (int jj = 0; jj < 32; ++jj) w2c[jj] = W2[(q * 32 + jj) * CD + f];

  // ---- phase 1: per-node gather in x-space
  int wv = tid >> 6, lane = tid & 63;
  int n = n0 + wv;
  int h = lane >> 3, fb = lane & 7;
  float ad = aldt[n * 8 + h];
  const float4* x4 = (const float4*)xt;
  float4 acc = make_float4(0.f, 0.f, 0.f, 0.f);
  float den = 0.f;
  int beg = rowptr[n], end = rowptr[n + 1];
  int idx = beg;
  for (; idx + 2 <= end; idx += 2) {
    int s0 = csr[idx], s1 = csr[idx + 1];
    float a0 = alst[s0 * 8 + h] + ad;
    float a1 = alst[s1 * 8 + h] + ad;
    float4 v0 = x4[s0 * 8 + fb];
    float4 v1 = x4[s1 * 8 + fb];
    a0 = a0 > 0.f ? a0 : 0.2f * a0;
    a1 = a1 > 0.f ? a1 : 0.2f * a1;
    float e0 = __expf(a0), e1 = __expf(a1);
    acc.x = fmaf(e1, v1.x, fmaf(e0, v0.x, acc.x));
    acc.y = fmaf(e1, v1.y, fmaf(e0, v0.y, acc.y));
    acc.z = fmaf(e1, v1.z, fmaf(e0, v0.z, acc.z));
    acc.w = fmaf(e1, v1.w, fmaf(e0, v0.w, acc.w));
    den += e0 + e1;
  }
  for (; idx <= end; ++idx) {             // leftover edge + self-loop
    int s = (idx < end) ? csr[idx] : n;
    float a = alst[s * 8 + h] + ad;
    a = a > 0.f ? a : 0.2f * a;
    float e = __expf(a);
    float4 v = x4[s * 8 + fb];
    acc.x = fmaf(e, v.x, acc.x);
    acc.y = fmaf(e, v.y, acc.y);
    acc.z = fmaf(e, v.z, acc.z);
    acc.w = fmaf(e, v.w, acc.w);
    den += e;
  }
  *(float4*)(aggs + wv * 256 + h * 32 + fb * 4) = acc;
  if (fb == 0) dens[wv * 8 + h] = den;
  __syncthreads();

  // ---- phase 2: rel1 = relu(aggx @ W1_head / den + b1); reads are broadcast
  int hj = j >> 5;
  #pragma unroll
  for (int g = 0; g < 4; ++g) {
    const float* ar = aggs + g * 256 + hj * 32;
    float a = 0.f;
    #pragma unroll
    for (int k = 0; k < 32; ++k) a = fmaf(ar[k], w1c[k], a);
    float v = fmaf(a, 1.f / dens[g * 8 + hj], bj);
    rels[g * 256 + j] = fmaxf(v, 0.f);
  }
  __syncthreads();

  // ---- phase 3: h2 = rel1 @ W2 (k-split over q, reduce via shuffle + LDS)
  float accg[4];
  #pragma unroll
  for (int g = 0; g < 4; ++g) {
    const float4* r4 = (const float4*)(rels + g * 256 + q * 32);
    float a = 0.f;
    #pragma unroll
    for (int jj = 0; jj < 8; ++jj) {
      float4 a4 = r4[jj];
      a = fmaf(a4.x, w2c[4 * jj], fmaf(a4.y, w2c[4 * jj + 1],
          fmaf(a4.z, w2c[4 * jj + 2], fmaf(a4.w, w2c[4 * jj + 3], a))));
    }
    a += __shfl_xor(a, 32, 64);
    accg[g] = a;
  }
  if ((tid & 32) == 0) {
    #pragma unroll
    for (int g = 0; g < 4; ++g) part[wv][g][f] = accg[g];
  }
  __syncthreads();
  if (tid < 128) {
    int g = tid >> 5, ff = tid & 31;
    float v = part[0][g][ff] + part[1][g][ff] + part[2][g][ff] + part[3][g][ff];
    int nn = n0 + g;
    h2[(size_t)t * NN * CD + nn * CD + ff] = v;
    float vs = v * as2[ff], vd = v * ad2[ff];
    #pragma unroll
    for (int m = 1; m < 32; m <<= 1) {
      vs += __shfl_xor(vs, m, 64);
      vd += __shfl_xor(vd, m, 64);
    }
    if (ff == 0) {
      al2s[(size_t)t * NN + nn] = vs;
      al2d[(size_t)t * NN + nn] = vd;
    }
  }
}

// ---------------- GAT layer 2 aggregation, all t: 32 threads per node ----------------------

__global__ __launch_bounds__(256) void k_agg2_8(const float* __restrict__ h2,
    const float* __restrict__ als, const float* __restrict__ ald,
    const int* __restrict__ rowptr, const int* __restrict__ csr,
    const float* __restrict__ b2, float* __restrict__ out) {
  int tid = threadIdx.x;
  int t = blockIdx.x & 7;
  int r = tid >> 5, f = tid & 31;
  int n = (blockIdx.x >> 3) * 8 + r;
  const float* h2t = h2 + (size_t)t * NN * CD;
  const float* alst = als + (size_t)t * NN;
  float ad = ald[(size_t)t * NN + n];
  float acc = 0.f, den = 0.f;
  int beg = rowptr[n], end = rowptr[n + 1];
  int idx = beg;
  for (; idx + 2 <= end; idx += 2) {
    int s0 = csr[idx], s1 = csr[idx + 1];
    float a0 = alst[s0] + ad;
    float a1 = alst[s1] + ad;
    float v0 = h2t[(size_t)s0 * CD + f];
    float v1 = h2t[(size_t)s1 * CD + f];
    a0 = a0 > 0.f ? a0 : 0.2f * a0;
    a1 = a1 > 0.f ? a1 : 0.2f * a1;
    float e0 = __expf(a0), e1 = __expf(a1);
    acc = fmaf(e1, v1, fmaf(e0, v0, acc));
    den += e0 + e1;
  }
  for (; idx <= end; ++idx) {
    int s = (idx < end) ? csr[idx] : n;
    float a = alst[s] + ad;
    a = a > 0.f ? a : 0.2f * a;
    float e = __expf(a);
    acc = fmaf(e, h2t[(size_t)s * CD + f], acc);
    den += e;
  }
  out[(size_t)t * NN * CD + (size_t)n * CD + f] = acc / den + b2[f];
}

// ---------------- LSTM, all t in one kernel: weights in VGPRs, h/c in LDS ------------------
// block = 16 nodes; thread = (slot, gate-row r). Loops t with block-local barriers.

__global__ __launch_bounds__(256) void k_lstm_all(const float* __restrict__ agg2o,
    const float* __restrict__ w_ih, const float* __restrict__ w_hh,
    const float* __restrict__ b_ih, const float* __restrict__ b_hh,
    float* __restrict__ out) {
  __shared__ float xs[16 * 32], hs[16 * 32], cs[16 * 32], pre[16 * 128];
  int tid = threadIdx.x;
  int slot = tid >> 7;
  int r = tid & 127;
  float4 wi[8], wh[8];
  const float4* wi4 = (const float4*)(w_ih + r * 32);
  const float4* wh4 = (const float4*)(w_hh + r * 32);
  #pragma unroll
  for (int q = 0; q < 8; ++q) { wi[q] = wi4[q]; wh[q] = wh4[q]; }
  float bias = b_ih[r] + b_hh[r];
  int base = blockIdx.x * 16;
  for (int i = tid; i < 512; i += 256) { hs[i] = 0.f; cs[i] = 0.f; }
  for (int t = 0; t < TT; ++t) {
    for (int i = tid; i < 512; i += 256) xs[i] = agg2o[(size_t)t * NN * 32 + base * 32 + i];
    __syncthreads();                 // xs/hs ready (also orders prior hs writes)
    #pragma unroll
    for (int g = 0; g < 8; ++g) {
      int nl = slot * 8 + g;
      const float4* xv4 = (const float4*)(xs + nl * 32);
      const float4* hv4 = (const float4*)(hs + nl * 32);
      float acc = bias;
      #pragma unroll
      for (int q = 0; q < 8; ++q) {
        float4 a = xv4[q], b = hv4[q];
        acc = fmaf(a.x, wi[q].x, acc);
        acc = fmaf(a.y, wi[q].y, acc);
        acc = fmaf(a.z, wi[q].z, acc);
        acc = fmaf(a.w, wi[q].w, acc);
        acc = fmaf(b.x, wh[q].x, acc);
        acc = fmaf(b.y, wh[q].y, acc);
        acc = fmaf(b.z, wh[q].z, acc);
        acc = fmaf(b.w, wh[q].w, acc);
      }
      pre[nl * 128 + r] = acc;
    }
    __syncthreads();                 // pre ready; also: everyone done reading hs
    for (int i = tid; i < 512; i += 256) {
      int nl = i >> 5, k = i & 31;
      float ai = pre[nl * 128 + k];
      float af = pre[nl * 128 + 32 + k];
      float ag = pre[nl * 128 + 64 + k];
      float ao = pre[nl * 128 + 96 + k];
      float ii = 1.f / (1.f + __expf(-ai));
      float ff = 1.f / (1.f + __expf(-af));
      float gg = tanhf(ag);
      float oo = 1.f / (1.f + __expf(-ao));
      float cn = fmaf(ff, cs[i], ii * gg);
      float hn = oo * tanhf(cn);
      cs[i] = cn; hs[i] = hn;
      out[(size_t)t * NN * 32 + base * 32 + i] = hn;
    }
  }
}

// ---------------- softmax over nodes, coalesced two-pass ----------------

__global__ __launch_bounds__(256) void k_sm_sum(const float* __restrict__ out, float* __restrict__ sums) {
  int t = blockIdx.y;
  const float4* b4 = (const float4*)(out + ((size_t)t * NN + blockIdx.x * 800) * CD);
  int tid = threadIdx.x;
  float4 s4 = make_float4(0.f, 0.f, 0.f, 0.f);
  for (int i = tid; i < 6400; i += 256) {
    float4 v = b4[i];
    s4.x += __expf(v.x); s4.y += __expf(v.y);
    s4.z += __expf(v.z); s4.w += __expf(v.w);
  }
  __shared__ float4 red[256];
  red[tid] = s4;
  __syncthreads();
  for (int off = 128; off >= 8; off >>= 1) {
    if (tid < off) {
      float4 o = red[tid + off];
      red[tid].x += o.x; red[tid].y += o.y; red[tid].z += o.z; red[tid].w += o.w;
    }
    __syncthreads();
  }
  if (tid < 8) {
    float4 v = red[tid];
    int c0 = tid * 4;
    atomicAdd(&sums[t * CD + c0 + 0], v.x);
    atomicAdd(&sums[t * CD + c0 + 1], v.y);
    atomicAdd(&sums[t * CD + c0 + 2], v.z);
    atomicAdd(&sums[t * CD + c0 + 3], v.w);
  }
}

__global__ __launch_bounds__(256) void k_sm_scale(float* __restrict__ out, const float* __restrict__ sums) {
  int t = blockIdx.y;
  __shared__ float inv[CD];
  int tid = threadIdx.x;
  if (tid < CD) inv[tid] = 1.f / sums[t * CD + tid];
  __syncthreads();
  float4* b4 = (float4*)(out + ((size_t)t * NN + blockIdx.x * 800) * CD);
  for (int i = tid; i < 6400; i += 256) {
    float4 v = b4[i];
    int c0 = (4 * i) & 31;
    v.x = __expf(v.x) * inv[c0];
    v.y = __expf(v.y) * inv[c0 + 1];
    v.z = __expf(v.z) * inv[c0 + 2];
    v.w = __expf(v.w) * inv[c0 + 3];
    b4[i] = v;
  }
}

// ---------------- launch ----------------

extern "C" void kernel_launch(void* const* d_in, const int* in_sizes, int n_in,
                              void* d_out, int out_size, void* d_ws, size_t ws_size,
                              hipStream_t stream) {
  const float* x   = (const float*)d_in[0];
  const float* W1  = (const float*)d_in[1];
  const float* as1 = (const float*)d_in[2];
  const float* ad1 = (const float*)d_in[3];
  const float* b1  = (const float*)d_in[4];
  const float* W2  = (const float*)d_in[5];
  const float* as2 = (const float*)d_in[6];
  const float* ad2 = (const float*)d_in[7];
  const float* b2  = (const float*)d_in[8];
  const float* wih = (const float*)d_in[9];
  const float* whh = (const float*)d_in[10];
  const float* bih = (const float*)d_in[11];
  const float* bhh = (const float*)d_in[12];
  const int*   ei  = (const int*)d_in[13];
  const int* srcp = ei;
  const int* dstp = ei + NE;
  float* out = (float*)d_out;

  float* ws = (float*)d_ws;
  float* al1s  = ws;  ws += (size_t)TT * NN * 8;
  float* al1d  = ws;  ws += (size_t)TT * NN * 8;
  float* h2    = ws;  ws += (size_t)TT * NN * CD;
  float* al2s  = ws;  ws += (size_t)TT * NN;
  float* al2d  = ws;  ws += (size_t)TT * NN;
  float* agg2o = ws;  ws += (size_t)TT * NN * CD;
  float* sums  = ws;  ws += TT * CD;       // memset with deg below (adjacent)
  float* wsrc  = ws;  ws += 256;
  float* wdst  = ws;  ws += 256;
  int* rowptr = (int*)ws;
  int* fill   = rowptr + NN + 1;
  int* csr    = fill + NN;
  int* deg    = csr + NE;

  hipMemsetAsync(sums, 0, TT * CD * sizeof(float), stream);
  hipMemsetAsync(deg, 0, NN * sizeof(int), stream);

  k_deg<<<(NE + 255) / 256, 256, 0, stream>>>(dstp, deg);
  k_scan<<<1, 1024, 0, stream>>>(deg, rowptr, fill);
  k_fill<<<(NE + 255) / 256, 256, 0, stream>>>(srcp, dstp, fill, csr);
  k_prew<<<1, 256, 0, stream>>>(W1, as1, ad1, wsrc, wdst);

  k_logits8<<<(NN / 32) * TT, 256, 0, stream>>>(x, wsrc, wdst, al1s, al1d);
  k_fused8<<<(NN / 4) * TT, 256, 0, stream>>>(x, W1, b1, W2, as2, ad2,
                                              al1s, al1d, rowptr, csr, h2, al2s, al2d);
  k_agg2_8<<<(NN / 8) * TT, 256, 0, stream>>>(h2, al2s, al2d, rowptr, csr, b2, agg2o);
  k_lstm_all<<<NN / 16, 256, 0, stream>>>(agg2o, wih, whh, bih, bhh, out);

  k_sm_sum<<<dim3(25, TT), 256, 0, stream>>>(out, sums);
  k_sm_scale<<<dim3(25, TT), 256, 0, stream>>>(out, sums);
}